// Round 3
// baseline (419.947 us; speedup 1.0000x reference)
//
#include <hip/hip_runtime.h>
#include <stdint.h>

typedef unsigned short ushort_t;
typedef short bf16x8 __attribute__((ext_vector_type(8)));
typedef float f32x4 __attribute__((ext_vector_type(4)));
typedef float f32x16 __attribute__((ext_vector_type(16)));

#define HW_ 16384

__device__ __forceinline__ float bf2f(ushort_t u){
  return __uint_as_float(((unsigned)u) << 16);
}
__device__ __forceinline__ ushort_t f2bf(float f){
  unsigned u = __float_as_uint(f);
  u += 0x7fffu + ((u >> 16) & 1u);
  return (ushort_t)(u >> 16);
}

// ---------------------------------------------------------------------------
// Wp layout (ushort elements):
//   [0      .. 36864)  : score hi A-frags,  mtg 0..1 = Ws rows 0..63
//   [36864  .. 110592) : gxy  hi A-frags,   mtg 0..3 = Wx0,Wx1,Wy0,Wy1
//   [110592 .. 184320) : gxy  lo A-frags,   same order
// Within a group: [mtg][ks 0..35][lane 0..63][j 0..7];
// co' = mtg*32 + (lane&31); tap = ks>>2; ci = (ks&3)*16 + (lane>>5)*8 + j.
// ---------------------------------------------------------------------------
__global__ __launch_bounds__(256) void k_repack(
    const float* __restrict__ Ws, const float* __restrict__ Wx,
    const float* __restrict__ Wy, ushort_t* __restrict__ Wp){
  int e = blockIdx.x*256 + threadIdx.x;
  if (e >= 6*36*64*8) return;
  int j = e & 7; int lane = (e >> 3) & 63; int tt = e >> 9;
  int ks = tt % 36; int mtg = tt / 36;
  int co = mtg*32 + (lane & 31);
  int tap = ks >> 2;
  int ci = (ks & 3)*16 + ((lane >> 5) & 1)*8 + j;
  const float* src; int c;
  if (co < 64)      { src = Ws; c = co;       }
  else if (co < 128){ src = Wx; c = co - 64;  }
  else              { src = Wy; c = co - 128; }
  float w = src[(c*64 + ci)*9 + tap];
  ushort_t hi = f2bf(w);
  if (mtg < 2){
    Wp[e] = hi;
  } else {
    int eg = e - 2*18432;
    Wp[36864  + eg] = hi;
    Wp[110592 + eg] = f2bf(w - bf2f(hi));
  }
}

// ---------------------------------------------------------------------------
// xT_hi/xT_lo[b][y][w][ci] (bf16) = split of fp32 x[b][ci][y][w].
// ---------------------------------------------------------------------------
__global__ __launch_bounds__(256) void k_transpose(
    const float* __restrict__ x, ushort_t* __restrict__ xTh,
    ushort_t* __restrict__ xTl){
  int b = blockIdx.y, y2 = blockIdx.x;
  int t = threadIdx.x;
  __shared__ float L[2*64*133];
  #pragma unroll
  for (int rep=0; rep<16; rep++){
    int o = rep*256 + t;                 // float4 chunk id 0..4095
    int yh = o >> 11; int ci = (o >> 5) & 63; int w4 = o & 31;
    int y = y2*2 + yh;
    f32x4 v = *(const f32x4*)(x + (((size_t)(b*64 + ci)*128 + y))*128 + w4*4);
    int base = (yh*64 + ci)*133 + w4*4;
    L[base+0]=v[0]; L[base+1]=v[1]; L[base+2]=v[2]; L[base+3]=v[3];
  }
  __syncthreads();
  #pragma unroll
  for (int rep=0; rep<8; rep++){
    int o = rep*256 + t;                 // 0..2047
    int yh = o >> 10; int w = (o >> 3) & 127; int c8 = o & 7;
    int y = y2*2 + yh;
    bf16x8 hv, lv;
    #pragma unroll
    for (int j=0;j<8;j++){
      float v = L[(yh*64 + c8*8 + j)*133 + w];
      ushort_t h = f2bf(v);
      hv[j] = (short)h;
      lv[j] = (short)f2bf(v - bf2f(h));
    }
    size_t d = (((size_t)(b*128 + y))*128 + w)*64 + c8*8;
    *(bf16x8*)&xTh[d] = hv;
    *(bf16x8*)&xTl[d] = lv;
  }
}

// ---------------------------------------------------------------------------
// Score conv staging: XL[4 rows][130 w (halo)][64 ci] bf16, oct-swizzled:
// element (row, w1, ci) at oct slot s = (ci>>3) ^ (w1&7).
// ---------------------------------------------------------------------------
__device__ __forceinline__ void stage_xl128(ushort_t* XL, const ushort_t* xTh,
                                            int b, int h0, int wid, int lane, int t){
  int y = h0 + wid - 1;
  const ushort_t* xTb = xTh + (size_t)b*(128*128*64);
  int ldsRow = (wid*130 + 1)*64;
  if (y >= 0 && y < 128){
    #pragma unroll
    for (int i=0;i<16;i++){
      int idx = i*64 + lane;
      int w1off = idx >> 3; int s = idx & 7;
      int osrc = s ^ ((w1off + 1) & 7);
      bf16x8 v = *(const bf16x8*)(xTb + ((size_t)(y*128 + w1off))*64 + osrc*8);
      *(bf16x8*)&XL[ldsRow + idx*8] = v;
    }
  } else {
    bf16x8 z = {0,0,0,0,0,0,0,0};
    #pragma unroll
    for (int i=0;i<16;i++)
      *(bf16x8*)&XL[ldsRow + (i*64 + lane)*8] = z;
  }
  if (t < 64){
    bf16x8 z = {0,0,0,0,0,0,0,0};
    int r = t >> 4; int sub = t & 15;
    int col = (sub >> 3) ? 129 : 0; int o = sub & 7;
    *(bf16x8*)&XL[(r*130 + col)*64 + o*8] = z;
  }
}

// ---------------------------------------------------------------------------
// Phase 1: score = conv(x, Ws) + bs -> ws (bf16). WG: 64co x 256px (2 rows).
// ---------------------------------------------------------------------------
__global__ __launch_bounds__(256, 2) void k_conv_score(
    const ushort_t* __restrict__ xTh, const ushort_t* __restrict__ Wp,
    const float* __restrict__ bs, ushort_t* __restrict__ score){
  int b = blockIdx.y; int h0 = blockIdx.x*2;
  int t = threadIdx.x; int lane = t & 63; int wid = t >> 6;
  int n = lane & 31; int kh = lane >> 5;
  __shared__ __align__(16) ushort_t XL[4*130*64];

  stage_xl128(XL, xTh, b, h0, wid, lane, t);
  __syncthreads();

  int mh = wid & 1; int nhb = (wid >> 1)*4;
  f32x16 acc[4];
  #pragma unroll
  for (int reg=0; reg<16; reg++){
    int row32 = (reg & 3) + 8*(reg >> 2) + 4*kh;
    float bv = bs[mh*32 + row32];
    #pragma unroll
    for (int ni=0; ni<4; ni++) acc[ni][reg] = bv;
  }

  const ushort_t* wpA = Wp + mh*36*512 + lane*8;
  #pragma unroll
  for (int rb=0; rb<3; rb++){
    #pragma unroll
    for (int kw=0; kw<3; kw++){
      int dw = kw - 1; int tap = rb*3 + kw;
      #pragma unroll
      for (int q=0; q<4; q++){
        int ks = tap*4 + q;
        bf16x8 a = *(const bf16x8*)(wpA + ks*512);
        int oo = q*2 + kh;
        #pragma unroll
        for (int ni=0; ni<4; ni++){
          int px = (nhb + ni)*32 + n;
          int hs = px >> 7; int w = px & 127;
          int w1 = w + dw + 1;
          bf16x8 bb = *(const bf16x8*)&XL[((rb + hs)*130 + w1)*64 + ((oo ^ (w1 & 7)) << 3)];
          acc[ni] = __builtin_amdgcn_mfma_f32_32x32x16_bf16(a, bb, acc[ni], 0, 0, 0);
        }
      }
    }
  }

  ushort_t* sb = score + (size_t)b*64*HW_;
  #pragma unroll
  for (int ni=0; ni<4; ni++){
    int px = (nhb + ni)*32 + n;
    int hs = px >> 7; int w = px & 127;
    int h = h0 + hs;
    #pragma unroll
    for (int reg=0; reg<16; reg++){
      int row32 = (reg & 3) + 8*(reg >> 2) + 4*kh;
      int co = mh*32 + row32;
      sb[(size_t)co*HW_ + h*128 + w] = f2bf(acc[ni][reg]);
    }
  }
}

// ---------------------------------------------------------------------------
// Phase 2: gx/gy = split-bf16 conv(x, Wx/Wy)+b (fp32-accurate), then bilinear
// sample of score -> out (fp32). WG: 128co' x (2 rows x 64 w).
// wave: mh = m-half (0:Wx,1:Wy), nh = n-half (output row). 3 MFMA/acc/step.
// ---------------------------------------------------------------------------
__global__ __launch_bounds__(256, 2) void k_gxy_sample(
    const ushort_t* __restrict__ xTh, const ushort_t* __restrict__ xTl,
    const ushort_t* __restrict__ Wp,
    const float* __restrict__ bx, const float* __restrict__ by,
    const ushort_t* __restrict__ score, float* __restrict__ out){
  int b = blockIdx.y;
  int h0 = (blockIdx.x >> 1)*2;
  int wq = (blockIdx.x & 1)*64;
  int t = threadIdx.x; int lane = t & 63; int wid = t >> 6;
  int n = lane & 31; int kh = lane >> 5;
  __shared__ __align__(16) ushort_t XL[2*4*66*64];  // hi @0, lo @16896 (67584 B)
  float* G = (float*)XL;                            // [128][68] f32 overlay

  const ushort_t* bhp = xTh + (size_t)b*(128*128*64);
  const ushort_t* blp = xTl + (size_t)b*(128*128*64);
  {
    int y = h0 + wid - 1;
    int rowBase = wid*66*64;
    if (y >= 0 && y < 128){
      #pragma unroll
      for (int i=0;i<8;i++){
        int idx = i*64 + lane;            // 0..511
        int wl = idx >> 3; int s = idx & 7; int w1 = wl + 1;
        int osrc = s ^ (w1 & 7);
        size_t g = ((size_t)(y*128 + wq + wl))*64 + osrc*8;
        *(bf16x8*)&XL[rowBase + w1*64 + s*8]         = *(const bf16x8*)&bhp[g];
        *(bf16x8*)&XL[16896 + rowBase + w1*64 + s*8] = *(const bf16x8*)&blp[g];
      }
    } else {
      bf16x8 z = {0,0,0,0,0,0,0,0};
      #pragma unroll
      for (int i=0;i<8;i++){
        int idx = i*64 + lane;
        int wl = idx >> 3; int s = idx & 7; int w1 = wl + 1;
        *(bf16x8*)&XL[rowBase + w1*64 + s*8] = z;
        *(bf16x8*)&XL[16896 + rowBase + w1*64 + s*8] = z;
      }
    }
    if (t < 64){
      int r = t >> 4; int sub = t & 15;
      int w1 = (sub >> 3) ? 65 : 0; int s = sub & 7;
      int yr = h0 + r - 1;
      int w  = wq + w1 - 1;
      int osrc = s ^ (w1 & 7);
      int dst = r*66*64 + w1*64 + s*8;
      if (yr >= 0 && yr < 128 && w >= 0 && w < 128){
        size_t g = ((size_t)(yr*128 + w))*64 + osrc*8;
        *(bf16x8*)&XL[dst]         = *(const bf16x8*)&bhp[g];
        *(bf16x8*)&XL[16896 + dst] = *(const bf16x8*)&blp[g];
      } else {
        bf16x8 z = {0,0,0,0,0,0,0,0};
        *(bf16x8*)&XL[dst] = z;
        *(bf16x8*)&XL[16896 + dst] = z;
      }
    }
  }
  __syncthreads();

  int mh = wid & 1; int nh = wid >> 1;
  f32x16 acc[2][2];
  #pragma unroll
  for (int mi=0; mi<2; mi++){
    #pragma unroll
    for (int reg=0; reg<16; reg++){
      int col = (mh*2+mi)*32 + (reg & 3) + 8*(reg >> 2) + 4*kh;
      float bv = (col < 64) ? bx[col] : by[col-64];
      #pragma unroll
      for (int ni=0; ni<2; ni++) acc[mi][ni][reg] = bv;
    }
  }

  int aBase0 = 36864 + (mh*2+0)*36*512 + lane*8;
  int aBase1 = 36864 + (mh*2+1)*36*512 + lane*8;
  #pragma unroll
  for (int rb=0; rb<3; rb++){
    #pragma unroll
    for (int kw=0; kw<3; kw++){
      int dw = kw - 1; int tap = rb*3 + kw;
      #pragma unroll
      for (int q=0; q<4; q++){
        int ks = tap*4 + q;
        bf16x8 ah0 = *(const bf16x8*)&Wp[aBase0 + ks*512];
        bf16x8 ah1 = *(const bf16x8*)&Wp[aBase1 + ks*512];
        bf16x8 al0 = *(const bf16x8*)&Wp[aBase0 + 73728 + ks*512];
        bf16x8 al1 = *(const bf16x8*)&Wp[aBase1 + 73728 + ks*512];
        int oo = q*2 + kh;
        int row = rb + nh;
        #pragma unroll
        for (int ni=0; ni<2; ni++){
          int wl = ni*32 + n;
          int w1 = wl + dw + 1;
          int off = (row*66 + w1)*64 + ((oo ^ (w1 & 7)) << 3);
          bf16x8 bh8 = *(const bf16x8*)&XL[off];
          bf16x8 bl8 = *(const bf16x8*)&XL[16896 + off];
          acc[0][ni] = __builtin_amdgcn_mfma_f32_32x32x16_bf16(ah0, bh8, acc[0][ni], 0,0,0);
          acc[0][ni] = __builtin_amdgcn_mfma_f32_32x32x16_bf16(al0, bh8, acc[0][ni], 0,0,0);
          acc[0][ni] = __builtin_amdgcn_mfma_f32_32x32x16_bf16(ah0, bl8, acc[0][ni], 0,0,0);
          acc[1][ni] = __builtin_amdgcn_mfma_f32_32x32x16_bf16(ah1, bh8, acc[1][ni], 0,0,0);
          acc[1][ni] = __builtin_amdgcn_mfma_f32_32x32x16_bf16(al1, bh8, acc[1][ni], 0,0,0);
          acc[1][ni] = __builtin_amdgcn_mfma_f32_32x32x16_bf16(ah1, bl8, acc[1][ni], 0,0,0);
        }
      }
    }
  }
  __syncthreads();   // XL reads done before G overlay writes

  const ushort_t* scB = score + (size_t)b*64*HW_;
  int wlt = t & 63; int cho = t >> 6;
  #pragma unroll 1
  for (int hs=0; hs<2; hs++){
    if (nh == hs){
      #pragma unroll
      for (int mi=0; mi<2; mi++){
        #pragma unroll
        for (int ni=0; ni<2; ni++){
          int wl = ni*32 + n;
          #pragma unroll
          for (int reg=0; reg<16; reg++){
            int col = (mh*2+mi)*32 + (reg & 3) + 8*(reg >> 2) + 4*kh;
            G[col*68 + wl] = acc[mi][ni][reg];
          }
        }
      }
    }
    __syncthreads();
    int h = h0 + hs;
    #pragma unroll 1
    for (int it=0; it<16; it++){
      int co = it*4 + cho;
      float gx = G[co*68 + wlt];
      float gy = G[(64 + co)*68 + wlt];
      float ix = ((gx + 1.0f)*128.0f - 1.0f)*0.5f;
      float iy = ((gy + 1.0f)*128.0f - 1.0f)*0.5f;
      float x0f = floorf(ix), y0f = floorf(iy);
      int x0 = (int)x0f, y0 = (int)y0f;
      float wx1 = ix - x0f, wy1 = iy - y0f;
      float wx0 = 1.0f - wx1, wy0 = 1.0f - wy1;
      const ushort_t* img = scB + (size_t)co*HW_;
      int x0c = min(max(x0,0),127), x1c = min(max(x0+1,0),127);
      int y0c = min(max(y0,0),127), y1c = min(max(y0+1,0),127);
      bool vx0 = (unsigned)x0 < 128u,  vx1 = (unsigned)(x0+1) < 128u;
      bool vy0 = (unsigned)y0 < 128u,  vy1 = (unsigned)(y0+1) < 128u;
      float v00 = (vy0 && vx0) ? bf2f(img[y0c*128 + x0c]) : 0.0f;
      float v01 = (vy0 && vx1) ? bf2f(img[y0c*128 + x1c]) : 0.0f;
      float v10 = (vy1 && vx0) ? bf2f(img[y1c*128 + x0c]) : 0.0f;
      float v11 = (vy1 && vx1) ? bf2f(img[y1c*128 + x1c]) : 0.0f;
      float r = v00*(wy0*wx0) + v01*(wy0*wx1) + v10*(wy1*wx0) + v11*(wy1*wx1);
      out[(((size_t)(b*64 + co))*128 + h)*128 + wq + wlt] = r;
    }
    __syncthreads();
  }
}

// ---------------------------------------------------------------------------
extern "C" void kernel_launch(void* const* d_in, const int* in_sizes, int n_in,
                              void* d_out, int out_size, void* d_ws, size_t ws_size,
                              hipStream_t stream){
  const float* x  = (const float*)d_in[0];
  const float* Ws = (const float*)d_in[1];
  const float* bs = (const float*)d_in[2];
  const float* Wx = (const float*)d_in[3];
  const float* bx = (const float*)d_in[4];
  const float* Wy = (const float*)d_in[5];
  const float* by = (const float*)d_in[6];
  float* out = (float*)d_out;
  ushort_t* ws  = (ushort_t*)d_ws;
  ushort_t* score = ws;                    // 16,777,216 bf16 = 33.5 MB
  ushort_t* xTh   = ws + 16777216;         // 33.5 MB
  ushort_t* xTl   = ws + 2*16777216;       // 33.5 MB
  ushort_t* Wp    = ws + 3*16777216;       // 184,320 bf16 = 0.37 MB

  k_repack    <<<dim3(432),    256, 0, stream>>>(Ws, Wx, Wy, Wp);
  k_transpose <<<dim3(64,16),  256, 0, stream>>>(x, xTh, xTl);
  k_conv_score<<<dim3(64,16),  256, 0, stream>>>(xTh, Wp, bs, score);
  k_gxy_sample<<<dim3(128,16), 256, 0, stream>>>(xTh, xTl, Wp, bx, by, score, out);
}

// Round 4
// 353.013 us; speedup vs baseline: 1.1896x; 1.1896x over previous
//
#include <hip/hip_runtime.h>
#include <stdint.h>

typedef unsigned short ushort_t;
typedef short bf16x8 __attribute__((ext_vector_type(8)));
typedef float f32x4 __attribute__((ext_vector_type(4)));
typedef float f32x16 __attribute__((ext_vector_type(16)));

#define HW_ 16384

__device__ __forceinline__ float bf2f(ushort_t u){
  return __uint_as_float(((unsigned)u) << 16);
}
__device__ __forceinline__ ushort_t f2bf(float f){
  unsigned u = __float_as_uint(f);
  u += 0x7fffu + ((u >> 16) & 1u);
  return (ushort_t)(u >> 16);
}

// ---------------------------------------------------------------------------
// Wp layout (ushort elements):
//   [0      .. 36864)  : score hi A-frags,  mtg 0..1 = Ws rows 0..63
//   [36864  .. 110592) : gxy  hi A-frags,   mtg 0..3 = Wx0,Wx1,Wy0,Wy1
//   [110592 .. 184320) : gxy  lo A-frags,   same order
// Within a group: [mtg][ks 0..35][lane 0..63][j 0..7];
// co' = mtg*32 + (lane&31); tap = ks>>2; ci = (ks&3)*16 + (lane>>5)*8 + j.
// ---------------------------------------------------------------------------
__global__ __launch_bounds__(256) void k_repack(
    const float* __restrict__ Ws, const float* __restrict__ Wx,
    const float* __restrict__ Wy, ushort_t* __restrict__ Wp){
  int e = blockIdx.x*256 + threadIdx.x;
  if (e >= 6*36*64*8) return;
  int j = e & 7; int lane = (e >> 3) & 63; int tt = e >> 9;
  int ks = tt % 36; int mtg = tt / 36;
  int co = mtg*32 + (lane & 31);
  int tap = ks >> 2;
  int ci = (ks & 3)*16 + ((lane >> 5) & 1)*8 + j;
  const float* src; int c;
  if (co < 64)      { src = Ws; c = co;       }
  else if (co < 128){ src = Wx; c = co - 64;  }
  else              { src = Wy; c = co - 128; }
  float w = src[(c*64 + ci)*9 + tap];
  ushort_t hi = f2bf(w);
  if (mtg < 2){
    Wp[e] = hi;
  } else {
    int eg = e - 2*18432;
    Wp[36864  + eg] = hi;
    Wp[110592 + eg] = f2bf(w - bf2f(hi));
  }
}

// ---------------------------------------------------------------------------
// xT_hi/xT_lo[b][y][w][ci] (bf16) = split of fp32 x[b][ci][y][w].
// Grid 1024 1-D, XCD-swizzled: b = (bid&7) + 8*(bid>>9).
// ---------------------------------------------------------------------------
__global__ __launch_bounds__(256) void k_transpose(
    const float* __restrict__ x, ushort_t* __restrict__ xTh,
    ushort_t* __restrict__ xTl){
  int bid = blockIdx.x;
  int idx = bid >> 3;
  int b  = (bid & 7) + 8*(idx >> 6);
  int y2 = idx & 63;
  int t = threadIdx.x;
  __shared__ float L[2*64*133];
  #pragma unroll
  for (int rep=0; rep<16; rep++){
    int o = rep*256 + t;                 // float4 chunk id 0..4095
    int yh = o >> 11; int ci = (o >> 5) & 63; int w4 = o & 31;
    int y = y2*2 + yh;
    f32x4 v = *(const f32x4*)(x + (((size_t)(b*64 + ci)*128 + y))*128 + w4*4);
    int base = (yh*64 + ci)*133 + w4*4;
    L[base+0]=v[0]; L[base+1]=v[1]; L[base+2]=v[2]; L[base+3]=v[3];
  }
  __syncthreads();
  #pragma unroll
  for (int rep=0; rep<8; rep++){
    int o = rep*256 + t;                 // 0..2047
    int yh = o >> 10; int w = (o >> 3) & 127; int c8 = o & 7;
    int y = y2*2 + yh;
    bf16x8 hv, lv;
    #pragma unroll
    for (int j=0;j<8;j++){
      float v = L[(yh*64 + c8*8 + j)*133 + w];
      ushort_t h = f2bf(v);
      hv[j] = (short)h;
      lv[j] = (short)f2bf(v - bf2f(h));
    }
    size_t d = (((size_t)(b*128 + y))*128 + w)*64 + c8*8;
    *(bf16x8*)&xTh[d] = hv;
    *(bf16x8*)&xTl[d] = lv;
  }
}

// ---------------------------------------------------------------------------
// Score conv staging: XL[4 rows][130 w (halo)][64 ci] bf16, oct-swizzled:
// element (row, w1, ci) at oct slot s = (ci>>3) ^ (w1&7).
// ---------------------------------------------------------------------------
__device__ __forceinline__ void stage_xl128(ushort_t* XL, const ushort_t* xTh,
                                            int b, int h0, int wid, int lane, int t){
  int y = h0 + wid - 1;
  const ushort_t* xTb = xTh + (size_t)b*(128*128*64);
  int ldsRow = (wid*130 + 1)*64;
  if (y >= 0 && y < 128){
    #pragma unroll
    for (int i=0;i<16;i++){
      int idx = i*64 + lane;
      int w1off = idx >> 3; int s = idx & 7;
      int osrc = s ^ ((w1off + 1) & 7);
      bf16x8 v = *(const bf16x8*)(xTb + ((size_t)(y*128 + w1off))*64 + osrc*8);
      *(bf16x8*)&XL[ldsRow + idx*8] = v;
    }
  } else {
    bf16x8 z = {0,0,0,0,0,0,0,0};
    #pragma unroll
    for (int i=0;i<16;i++)
      *(bf16x8*)&XL[ldsRow + (i*64 + lane)*8] = z;
  }
  if (t < 64){
    bf16x8 z = {0,0,0,0,0,0,0,0};
    int r = t >> 4; int sub = t & 15;
    int col = (sub >> 3) ? 129 : 0; int o = sub & 7;
    *(bf16x8*)&XL[(r*130 + col)*64 + o*8] = z;
  }
}

// ---------------------------------------------------------------------------
// Phase 1: score = conv(x, Ws) + bs -> ws (bf16). WG: 64co x 256px (2 rows).
// Grid 1024 1-D, XCD-swizzled.
// ---------------------------------------------------------------------------
__global__ __launch_bounds__(256, 2) void k_conv_score(
    const ushort_t* __restrict__ xTh, const ushort_t* __restrict__ Wp,
    const float* __restrict__ bs, ushort_t* __restrict__ score){
  int bid = blockIdx.x;
  int idx = bid >> 3;
  int b  = (bid & 7) + 8*(idx >> 6);
  int h0 = (idx & 63)*2;
  int t = threadIdx.x; int lane = t & 63; int wid = t >> 6;
  int n = lane & 31; int kh = lane >> 5;
  __shared__ __align__(16) ushort_t XL[4*130*64];

  stage_xl128(XL, xTh, b, h0, wid, lane, t);
  __syncthreads();

  int mh = wid & 1; int nhb = (wid >> 1)*4;
  f32x16 acc[4];
  #pragma unroll
  for (int reg=0; reg<16; reg++){
    int row32 = (reg & 3) + 8*(reg >> 2) + 4*kh;
    float bv = bs[mh*32 + row32];
    #pragma unroll
    for (int ni=0; ni<4; ni++) acc[ni][reg] = bv;
  }

  const ushort_t* wpA = Wp + mh*36*512 + lane*8;
  #pragma unroll
  for (int rb=0; rb<3; rb++){
    #pragma unroll
    for (int kw=0; kw<3; kw++){
      int dw = kw - 1; int tap = rb*3 + kw;
      #pragma unroll
      for (int q=0; q<4; q++){
        int ks = tap*4 + q;
        bf16x8 a = *(const bf16x8*)(wpA + ks*512);
        int oo = q*2 + kh;
        #pragma unroll
        for (int ni=0; ni<4; ni++){
          int px = (nhb + ni)*32 + n;
          int hs = px >> 7; int w = px & 127;
          int w1 = w + dw + 1;
          bf16x8 bb = *(const bf16x8*)&XL[((rb + hs)*130 + w1)*64 + ((oo ^ (w1 & 7)) << 3)];
          acc[ni] = __builtin_amdgcn_mfma_f32_32x32x16_bf16(a, bb, acc[ni], 0, 0, 0);
        }
      }
    }
  }

  ushort_t* sb = score + (size_t)b*64*HW_;
  #pragma unroll
  for (int ni=0; ni<4; ni++){
    int px = (nhb + ni)*32 + n;
    int hs = px >> 7; int w = px & 127;
    int h = h0 + hs;
    #pragma unroll
    for (int reg=0; reg<16; reg++){
      int row32 = (reg & 3) + 8*(reg >> 2) + 4*kh;
      int co = mh*32 + row32;
      sb[(size_t)co*HW_ + h*128 + w] = f2bf(acc[ni][reg]);
    }
  }
}

// ---------------------------------------------------------------------------
// Phase 2: gx/gy = split-bf16 conv(x, Wx/Wy)+b (fp32-accurate), then bilinear
// sample of score -> out (fp32). WG: 128co' x (2 rows x 64 w).
// Grid 2048 1-D, XCD-swizzled: all WGs of one b on one XCD, b-major order.
// ---------------------------------------------------------------------------
__global__ __launch_bounds__(256, 2) void k_gxy_sample(
    const ushort_t* __restrict__ xTh, const ushort_t* __restrict__ xTl,
    const ushort_t* __restrict__ Wp,
    const float* __restrict__ bx, const float* __restrict__ by,
    const ushort_t* __restrict__ score, float* __restrict__ out){
  int bid = blockIdx.x;
  int idx = bid >> 3;          // 0..255
  int b   = (bid & 7) + 8*(idx >> 7);
  int rest = idx & 127;
  int h0 = (rest >> 1)*2;
  int wq = (rest & 1)*64;
  int t = threadIdx.x; int lane = t & 63; int wid = t >> 6;
  int n = lane & 31; int kh = lane >> 5;
  __shared__ __align__(16) ushort_t XL[2*4*66*64];  // hi @0, lo @16896 (67584 B)
  float* G = (float*)XL;                            // [128][68] f32 overlay

  const ushort_t* bhp = xTh + (size_t)b*(128*128*64);
  const ushort_t* blp = xTl + (size_t)b*(128*128*64);
  {
    int y = h0 + wid - 1;
    int rowBase = wid*66*64;
    if (y >= 0 && y < 128){
      #pragma unroll
      for (int i=0;i<8;i++){
        int idx2 = i*64 + lane;           // 0..511
        int wl = idx2 >> 3; int s = idx2 & 7; int w1 = wl + 1;
        int osrc = s ^ (w1 & 7);
        size_t g = ((size_t)(y*128 + wq + wl))*64 + osrc*8;
        *(bf16x8*)&XL[rowBase + w1*64 + s*8]         = *(const bf16x8*)&bhp[g];
        *(bf16x8*)&XL[16896 + rowBase + w1*64 + s*8] = *(const bf16x8*)&blp[g];
      }
    } else {
      bf16x8 z = {0,0,0,0,0,0,0,0};
      #pragma unroll
      for (int i=0;i<8;i++){
        int idx2 = i*64 + lane;
        int wl = idx2 >> 3; int s = idx2 & 7; int w1 = wl + 1;
        *(bf16x8*)&XL[rowBase + w1*64 + s*8] = z;
        *(bf16x8*)&XL[16896 + rowBase + w1*64 + s*8] = z;
      }
    }
    if (t < 64){
      int r = t >> 4; int sub = t & 15;
      int w1 = (sub >> 3) ? 65 : 0; int s = sub & 7;
      int yr = h0 + r - 1;
      int w  = wq + w1 - 1;
      int osrc = s ^ (w1 & 7);
      int dst = r*66*64 + w1*64 + s*8;
      if (yr >= 0 && yr < 128 && w >= 0 && w < 128){
        size_t g = ((size_t)(yr*128 + w))*64 + osrc*8;
        *(bf16x8*)&XL[dst]         = *(const bf16x8*)&bhp[g];
        *(bf16x8*)&XL[16896 + dst] = *(const bf16x8*)&blp[g];
      } else {
        bf16x8 z = {0,0,0,0,0,0,0,0};
        *(bf16x8*)&XL[dst] = z;
        *(bf16x8*)&XL[16896 + dst] = z;
      }
    }
  }
  __syncthreads();

  int mh = wid & 1; int nh = wid >> 1;
  f32x16 acc[2][2];
  #pragma unroll
  for (int mi=0; mi<2; mi++){
    #pragma unroll
    for (int reg=0; reg<16; reg++){
      int col = (mh*2+mi)*32 + (reg & 3) + 8*(reg >> 2) + 4*kh;
      float bv = (col < 64) ? bx[col] : by[col-64];
      #pragma unroll
      for (int ni=0; ni<2; ni++) acc[mi][ni][reg] = bv;
    }
  }

  int aBase0 = 36864 + (mh*2+0)*36*512 + lane*8;
  int aBase1 = 36864 + (mh*2+1)*36*512 + lane*8;
  #pragma unroll
  for (int rb=0; rb<3; rb++){
    #pragma unroll
    for (int kw=0; kw<3; kw++){
      int dw = kw - 1; int tap = rb*3 + kw;
      #pragma unroll
      for (int q=0; q<4; q++){
        int ks = tap*4 + q;
        bf16x8 ah0 = *(const bf16x8*)&Wp[aBase0 + ks*512];
        bf16x8 ah1 = *(const bf16x8*)&Wp[aBase1 + ks*512];
        bf16x8 al0 = *(const bf16x8*)&Wp[aBase0 + 73728 + ks*512];
        bf16x8 al1 = *(const bf16x8*)&Wp[aBase1 + 73728 + ks*512];
        int oo = q*2 + kh;
        int row = rb + nh;
        #pragma unroll
        for (int ni=0; ni<2; ni++){
          int wl = ni*32 + n;
          int w1 = wl + dw + 1;
          int off = (row*66 + w1)*64 + ((oo ^ (w1 & 7)) << 3);
          bf16x8 bh8 = *(const bf16x8*)&XL[off];
          bf16x8 bl8 = *(const bf16x8*)&XL[16896 + off];
          acc[0][ni] = __builtin_amdgcn_mfma_f32_32x32x16_bf16(ah0, bh8, acc[0][ni], 0,0,0);
          acc[0][ni] = __builtin_amdgcn_mfma_f32_32x32x16_bf16(al0, bh8, acc[0][ni], 0,0,0);
          acc[0][ni] = __builtin_amdgcn_mfma_f32_32x32x16_bf16(ah0, bl8, acc[0][ni], 0,0,0);
          acc[1][ni] = __builtin_amdgcn_mfma_f32_32x32x16_bf16(ah1, bh8, acc[1][ni], 0,0,0);
          acc[1][ni] = __builtin_amdgcn_mfma_f32_32x32x16_bf16(al1, bh8, acc[1][ni], 0,0,0);
          acc[1][ni] = __builtin_amdgcn_mfma_f32_32x32x16_bf16(ah1, bl8, acc[1][ni], 0,0,0);
        }
      }
    }
  }
  __syncthreads();   // XL reads done before G overlay writes

  const ushort_t* scB = score + (size_t)b*64*HW_;
  int wlt = t & 63; int cho = t >> 6;
  #pragma unroll 1
  for (int hs=0; hs<2; hs++){
    if (nh == hs){
      #pragma unroll
      for (int mi=0; mi<2; mi++){
        #pragma unroll
        for (int ni=0; ni<2; ni++){
          int wl = ni*32 + n;
          #pragma unroll
          for (int reg=0; reg<16; reg++){
            int col = (mh*2+mi)*32 + (reg & 3) + 8*(reg >> 2) + 4*kh;
            G[col*68 + wl] = acc[mi][ni][reg];
          }
        }
      }
    }
    __syncthreads();
    int h = h0 + hs;
    #pragma unroll 4
    for (int it=0; it<16; it++){
      int co = it*4 + cho;
      float gx = G[co*68 + wlt];
      float gy = G[(64 + co)*68 + wlt];
      float ix = ((gx + 1.0f)*128.0f - 1.0f)*0.5f;
      float iy = ((gy + 1.0f)*128.0f - 1.0f)*0.5f;
      float x0f = floorf(ix), y0f = floorf(iy);
      int x0 = (int)x0f, y0 = (int)y0f;
      float wx1 = ix - x0f, wy1 = iy - y0f;
      float wx0 = 1.0f - wx1, wy0 = 1.0f - wy1;
      const ushort_t* img = scB + (size_t)co*HW_;
      int x0c = min(max(x0,0),127), x1c = min(max(x0+1,0),127);
      int y0c = min(max(y0,0),127), y1c = min(max(y0+1,0),127);
      bool vx0 = (unsigned)x0 < 128u,  vx1 = (unsigned)(x0+1) < 128u;
      bool vy0 = (unsigned)y0 < 128u,  vy1 = (unsigned)(y0+1) < 128u;
      float v00 = (vy0 && vx0) ? bf2f(img[y0c*128 + x0c]) : 0.0f;
      float v01 = (vy0 && vx1) ? bf2f(img[y0c*128 + x1c]) : 0.0f;
      float v10 = (vy1 && vx0) ? bf2f(img[y1c*128 + x0c]) : 0.0f;
      float v11 = (vy1 && vx1) ? bf2f(img[y1c*128 + x1c]) : 0.0f;
      float r = v00*(wy0*wx0) + v01*(wy0*wx1) + v10*(wy1*wx0) + v11*(wy1*wx1);
      out[(((size_t)(b*64 + co))*128 + h)*128 + wq + wlt] = r;
    }
    __syncthreads();
  }
}

// ---------------------------------------------------------------------------
extern "C" void kernel_launch(void* const* d_in, const int* in_sizes, int n_in,
                              void* d_out, int out_size, void* d_ws, size_t ws_size,
                              hipStream_t stream){
  const float* x  = (const float*)d_in[0];
  const float* Ws = (const float*)d_in[1];
  const float* bs = (const float*)d_in[2];
  const float* Wx = (const float*)d_in[3];
  const float* bx = (const float*)d_in[4];
  const float* Wy = (const float*)d_in[5];
  const float* by = (const float*)d_in[6];
  float* out = (float*)d_out;
  ushort_t* ws  = (ushort_t*)d_ws;
  ushort_t* score = ws;                    // 16,777,216 bf16 = 33.5 MB
  ushort_t* xTh   = ws + 16777216;         // 33.5 MB
  ushort_t* xTl   = ws + 2*16777216;       // 33.5 MB
  ushort_t* Wp    = ws + 3*16777216;       // 184,320 bf16 = 0.37 MB

  k_repack    <<<dim3(432),  256, 0, stream>>>(Ws, Wx, Wy, Wp);
  k_transpose <<<dim3(1024), 256, 0, stream>>>(x, xTh, xTl);
  k_conv_score<<<dim3(1024), 256, 0, stream>>>(xTh, Wp, bs, score);
  k_gxy_sample<<<dim3(2048), 256, 0, stream>>>(xTh, xTl, Wp, bx, by, score, out);
}